// Round 7
// baseline (361.253 us; speedup 1.0000x reference)
//
#include <hip/hip_runtime.h>

#define DEV __device__ __forceinline__

typedef __attribute__((ext_vector_type(4))) float f32x4;
typedef __attribute__((ext_vector_type(4))) unsigned short u16x4;
typedef __attribute__((ext_vector_type(8))) __bf16 bf16x8;

constexpr int NB = 16, SL = 2048, EM = 1024, DKD = 128;

DEV unsigned short f2bf(float f) {           // fp32 -> bf16 RNE
  unsigned int u = __float_as_uint(f);
  u += 0x7FFFu + ((u >> 16) & 1u);
  return (unsigned short)(u >> 16);
}

DEV f32x4 mfma16(bf16x8 a, bf16x8 b, f32x4 c) {
  return __builtin_amdgcn_mfma_f32_16x16x32_bf16(a, b, c, 0, 0, 0);
}

// async global->LDS DMA, 16B per lane; lds dst = wave-uniform base + lane*16
DEV void dma16(const void* g, void* l) {
  __builtin_amdgcn_global_load_lds(
      (const __attribute__((address_space(1))) unsigned int*)g,
      (__attribute__((address_space(3))) unsigned int*)l, 16, 0, 0);
}

DEV bf16x8 cvt8(f32x4 a, f32x4 b) {
  bf16x8 r;
  r[0] = (__bf16)a[0]; r[1] = (__bf16)a[1]; r[2] = (__bf16)a[2]; r[3] = (__bf16)a[3];
  r[4] = (__bf16)b[0]; r[5] = (__bf16)b[1]; r[6] = (__bf16)b[2]; r[7] = (__bf16)b[3];
  return r;
}

#define SBAR() __builtin_amdgcn_sched_barrier(0)

// ---------------------------------------------------------------------------
// prep_w: Wq/Wk/Wv fp32 [1024][128] -> bf16, tiled+swizzled. Block 0 also
// zeroes the mean-V accumulator mvg[NB][128].
// Chunk t = ((m*16 + kc)*128 + n)*8 + p holds W_m[k = kc*64 + (p^(n&7))*8 + e][n].
// ---------------------------------------------------------------------------
__global__ __launch_bounds__(256) void prep_w(
    const float* __restrict__ Wq, const float* __restrict__ Wk,
    const float* __restrict__ Wv, unsigned short* __restrict__ Wt,
    float* __restrict__ mvg)
{
  __shared__ unsigned short T[64 * 128];     // [kk][n] bf16
  const int tid = threadIdx.x;
  if (blockIdx.x == 0) {
    #pragma unroll
    for (int i = 0; i < NB * DKD / 256; ++i) mvg[i * 256 + tid] = 0.f;
  }
  const int m = blockIdx.x >> 4, kc = blockIdx.x & 15;   // 48 blocks
  const float* W = (m == 0) ? Wq : ((m == 1) ? Wk : Wv);
  #pragma unroll
  for (int it = 0; it < 8; ++it) {
    int idx = it * 256 + tid;                // 2048 f32x4 chunks
    int kk = idx >> 5, n4 = (idx & 31) * 4;
    f32x4 w4 = *(const f32x4*)(W + (size_t)(kc * 64 + kk) * DKD + n4);
    *(u16x4*)&T[kk * 128 + n4] =
        u16x4{ f2bf(w4[0]), f2bf(w4[1]), f2bf(w4[2]), f2bf(w4[3]) };
  }
  __syncthreads();
  #pragma unroll
  for (int it = 0; it < 4; ++it) {
    int idx = it * 256 + tid;                // 1024 out chunks, p fastest
    int p = idx & 7, n = idx >> 3;
    int c = p ^ (n & 7);
    unsigned short v[8];
    #pragma unroll
    for (int e = 0; e < 8; ++e) v[e] = T[(c * 8 + e) * 128 + n];
    size_t t = ((size_t)(m * 16 + kc) * 128 + n) * 8 + p;
    *(u16x4*)(Wt + t * 8)     = u16x4{v[0], v[1], v[2], v[3]};
    *(u16x4*)(Wt + t * 8 + 4) = u16x4{v[4], v[5], v[6], v[7]};
  }
}

// ---------------------------------------------------------------------------
// proj (merged): blockIdx&1 == 0 -> Q,K = ctx @ {Wq,Wk}; == 1 -> V = x @ Wv.
// BATCH-FASTEST tile map: bi=(blockIdx>>1), b=bi&15, t=bi>>4 -> consecutive
// blockIdx mix all batches, so dead blocks (t*64>=len) spread uniformly
// across CUs (load balance; was clustered per batch = 9% occupancy).
// A dbuf'd in LDS (full-iter DMA prefetch); B double-buffered in registers
// from the L2-resident pre-swizzled Wt.
// ---------------------------------------------------------------------------
#define QK_STEP(KC, BCUR, BNXT)                                               \
  {                                                                           \
    SBAR();                                                                   \
    bf16x8 af[4][2];                                                          \
    _Pragma("unroll")                                                         \
    for (int rt = 0; rt < 4; ++rt) {                                          \
      const float* rbase = Als[(KC) & 1] + (rt * 16 + mm) * 64;               \
      _Pragma("unroll")                                                       \
      for (int ks = 0; ks < 2; ++ks) {                                        \
        f32x4 a0 = *(const f32x4*)(rbase + soff[ks][0]);                      \
        f32x4 a1 = *(const f32x4*)(rbase + soff[ks][1]);                      \
        af[rt][ks] = cvt8(a0, a1);                                            \
      }                                                                       \
    }                                                                         \
    __asm__ volatile("s_waitcnt lgkmcnt(0)" ::: "memory");                    \
    SBAR();                                                                   \
    __builtin_amdgcn_s_barrier();            /* safe to overwrite Als[kc&1] */\
    {                                                                         \
      const int kn = ((KC) + 2 < 16) ? ((KC) + 2) : 15;                       \
      _Pragma("unroll")                                                       \
      for (int i = 0; i < 4; ++i)                                             \
        dma16(asrc[i] + kn * 64,                                              \
              (char*)Als[(KC) & 1] + wave * 4096 + i * 1024);                 \
    }                                                                         \
    {                                                                         \
      const int kb1 = ((KC) + 1 < 16) ? ((KC) + 1) : 15;                      \
      _Pragma("unroll")                                                       \
      for (int lo = 0; lo < 4; ++lo)                                          \
        _Pragma("unroll")                                                     \
        for (int ks = 0; ks < 2; ++ks)                                        \
          BNXT[lo][ks] = *(const bf16x8*)(bbase[lo][ks] + (size_t)kb1 * 8192);\
    }                                                                         \
    _Pragma("unroll")                                                         \
    for (int lo = 0; lo < 4; ++lo)                                            \
      _Pragma("unroll")                                                       \
      for (int ks = 0; ks < 2; ++ks)                                          \
        _Pragma("unroll")                                                     \
        for (int rt = 0; rt < 4; ++rt)                                        \
          acc[rt][lo] = mfma16(af[rt][ks], BCUR[lo][ks], acc[rt][lo]);        \
    __builtin_amdgcn_s_barrier();            /* A(kc+1) visible everywhere */ \
  }

#define V_STEP(KC, BCUR, BNXT)                                                \
  {                                                                           \
    SBAR();                                                                   \
    bf16x8 af[4][2];                                                          \
    _Pragma("unroll")                                                         \
    for (int rt = 0; rt < 4; ++rt) {                                          \
      const float* rbase = Als[(KC) & 1] + (rt * 16 + mm) * 64;               \
      _Pragma("unroll")                                                       \
      for (int ks = 0; ks < 2; ++ks) {                                        \
        f32x4 a0 = *(const f32x4*)(rbase + soff[ks][0]);                      \
        f32x4 a1 = *(const f32x4*)(rbase + soff[ks][1]);                      \
        af[rt][ks] = cvt8(a0, a1);                                            \
      }                                                                       \
    }                                                                         \
    __asm__ volatile("s_waitcnt lgkmcnt(0)" ::: "memory");                    \
    SBAR();                                                                   \
    __builtin_amdgcn_s_barrier();                                             \
    {                                                                         \
      const int kn = ((KC) + 2 < 16) ? ((KC) + 2) : 15;                       \
      _Pragma("unroll")                                                       \
      for (int i = 0; i < 4; ++i)                                             \
        dma16(asrc[i] + kn * 64,                                              \
              (char*)Als[(KC) & 1] + wave * 4096 + i * 1024);                 \
    }                                                                         \
    {                                                                         \
      const int kb1 = ((KC) + 1 < 16) ? ((KC) + 1) : 15;                      \
      _Pragma("unroll")                                                       \
      for (int lo = 0; lo < 2; ++lo)                                          \
        _Pragma("unroll")                                                     \
        for (int ks = 0; ks < 2; ++ks)                                        \
          BNXT[lo][ks] = *(const bf16x8*)(bbase[lo][ks] + (size_t)kb1 * 8192);\
    }                                                                         \
    _Pragma("unroll")                                                         \
    for (int lo = 0; lo < 2; ++lo)                                            \
      _Pragma("unroll")                                                       \
      for (int ks = 0; ks < 2; ++ks)                                          \
        _Pragma("unroll")                                                     \
        for (int rt = 0; rt < 4; ++rt)                                        \
          acc[rt][lo] = mfma16(af[rt][ks], BCUR[lo][ks], acc[rt][lo]);        \
    __builtin_amdgcn_s_barrier();                                             \
  }

__global__ __launch_bounds__(256, 2) void proj(
    const float* __restrict__ ctx, const float* __restrict__ x,
    const unsigned short* __restrict__ Wt, const int* __restrict__ lens,
    unsigned short* __restrict__ Qo, unsigned short* __restrict__ Kz,
    unsigned short* __restrict__ Vz, float* __restrict__ mvg)
{
  __shared__ float Als[2][64 * 64];            // 32 KiB A dbuf
  const int tid = threadIdx.x;
  const int wave = tid >> 6, lane = tid & 63;
  const int quad = lane >> 4, mm = lane & 15;
  const int isv = blockIdx.x & 1;
  const int bi  = (int)blockIdx.x >> 1;        // 0..511 tile index
  const int bidx = bi & 15;                    // batch (fast dim -> balance)
  const int tt   = bi >> 4;                    // 0..31 tile within batch
  const int len = lens[bidx];
  if (tt * 64 >= len) return;                  // dead block: outputs never read
  const int rb = bidx * SL + tt * 64;

  const float* Ain = isv ? x : ctx;

  // A-DMA source: instr i covers rows wave*16+i*4+(lane>>4); slot s=lane&15
  // sources chunk c=(s&8)|((s&7)^(row&7))  (involution, undone on read).
  const float* asrc[4];
  #pragma unroll
  for (int i = 0; i < 4; ++i) {
    const int rl_ = wave * 16 + i * 4 + (lane >> 4);
    const int cc  = (lane & 8) | ((lane & 7) ^ (rl_ & 7));
    asrc[i] = Ain + (size_t)(rb + rl_) * EM + cc * 4;
  }
  int soff[2][2];
  #pragma unroll
  for (int ks = 0; ks < 2; ++ks) {
    soff[ks][0] = (ks * 8 + ((quad * 2)     ^ (mm & 7))) * 4;
    soff[ks][1] = (ks * 8 + ((quad * 2 + 1) ^ (mm & 7))) * 4;
  }

  // ---- prologue: A(0)->Als[0], A(1)->Als[1]; wait A(0) (A(1) rides) ----
  #pragma unroll
  for (int i = 0; i < 4; ++i)
    dma16(asrc[i],      (char*)Als[0] + wave * 4096 + i * 1024);
  #pragma unroll
  for (int i = 0; i < 4; ++i)
    dma16(asrc[i] + 64, (char*)Als[1] + wave * 4096 + i * 1024);
  __asm__ volatile("s_waitcnt vmcnt(4)" ::: "memory");
  __builtin_amdgcn_s_barrier();

  if (!isv) {
    // ================= Q,K path =================
    f32x4 acc[4][4];
    #pragma unroll
    for (int i = 0; i < 4; ++i)
      #pragma unroll
      for (int j = 0; j < 4; ++j) acc[i][j] = f32x4{0.f, 0.f, 0.f, 0.f};

    const unsigned short* bbase[4][2];
    #pragma unroll
    for (int lo = 0; lo < 4; ++lo)
      #pragma unroll
      for (int ks = 0; ks < 2; ++ks) {
        const int nrow = (wave * 4 + lo) * 16 + mm;
        const int pp = (ks * 4 + quad) ^ (mm & 7);
        const int cs = nrow * 8 + pp;
        bbase[lo][ks] = Wt + ((size_t)(cs >> 10) * 16384 + (cs & 1023)) * 8;
      }
    bf16x8 bA[4][2], bB[4][2];
    #pragma unroll
    for (int lo = 0; lo < 4; ++lo)
      #pragma unroll
      for (int ks = 0; ks < 2; ++ks)
        bA[lo][ks] = *(const bf16x8*)(bbase[lo][ks]);   // B(0)

    #pragma unroll 1
    for (int t = 0; t < 8; ++t) {
      QK_STEP(2 * t,     bA, bB)
      QK_STEP(2 * t + 1, bB, bA)
    }
    __asm__ volatile("s_waitcnt vmcnt(0)" ::: "memory"); // drain clamped tail

    const float SCALE = 1.4426950408889634f * 0.08838834764831845f;
    #pragma unroll
    for (int rt = 0; rt < 4; ++rt)
      #pragma unroll
      for (int lo = 0; lo < 4; ++lo) {
        const int ctg = wave * 4 + lo;
        #pragma unroll
        for (int reg = 0; reg < 4; ++reg) {
          const int row = rb + rt * 16 + quad * 4 + reg;
          const int j = row & (SL - 1);
          const float val = acc[rt][lo][reg];
          if (ctg < 8) {
            const int d = ctg * 16 + mm;
            Qo[(size_t)row * DKD + d] = f2bf(val * ((j < len) ? SCALE : 0.f));
          } else {
            const int d = (ctg - 8) * 16 + mm;
            Kz[(size_t)row * DKD + (((d >> 3) ^ (j & 15)) * 8) + (d & 7)] = f2bf(val);
          }
        }
      }
  } else {
    // ================= V path =================
    f32x4 acc[4][2];
    #pragma unroll
    for (int i = 0; i < 4; ++i) {
      acc[i][0] = f32x4{0.f,0.f,0.f,0.f};
      acc[i][1] = f32x4{0.f,0.f,0.f,0.f};
    }
    const unsigned short* bbase[2][2];
    #pragma unroll
    for (int lo = 0; lo < 2; ++lo)
      #pragma unroll
      for (int ks = 0; ks < 2; ++ks) {
        const int nrow = (wave * 2 + lo) * 16 + mm;
        const int pp = (ks * 4 + quad) ^ (mm & 7);
        const int cs = nrow * 8 + pp;            // cs < 1024
        bbase[lo][ks] = Wt + ((size_t)2 * 16384 + cs) * 8;
      }
    bf16x8 bA[2][2], bB[2][2];
    #pragma unroll
    for (int lo = 0; lo < 2; ++lo)
      #pragma unroll
      for (int ks = 0; ks < 2; ++ks)
        bA[lo][ks] = *(const bf16x8*)(bbase[lo][ks]);   // B(0)

    #pragma unroll 1
    for (int t = 0; t < 8; ++t) {
      V_STEP(2 * t,     bA, bB)
      V_STEP(2 * t + 1, bB, bA)
    }
    __asm__ volatile("s_waitcnt vmcnt(0)" ::: "memory");

    #pragma unroll
    for (int rt = 0; rt < 4; ++rt)
      #pragma unroll
      for (int lo = 0; lo < 2; ++lo) {
        const int d = (wave * 2 + lo) * 16 + mm;
        const int row0 = rb + rt * 16 + quad * 4;
        const int b = row0 >> 11, j0 = row0 & (SL - 1);
        u16x4 pk = u16x4{ f2bf(acc[rt][lo][0]), f2bf(acc[rt][lo][1]),
                          f2bf(acc[rt][lo][2]), f2bf(acc[rt][lo][3]) };
        size_t off = (size_t)b * DKD * SL + (size_t)d * SL + (j0 & ~63)
                   + ((((j0 >> 3) & 7) ^ (d & 7)) * 8) + (j0 & 7);
        *(u16x4*)(Vz + off) = pk;
      }

    // mean-V accumulation: sum valid rows (j < len), f32, one atomic/(d)
    const int jb = rb & (SL - 1);
    #pragma unroll
    for (int lo = 0; lo < 2; ++lo) {
      const int d = (wave * 2 + lo) * 16 + mm;
      float part = 0.f;
      #pragma unroll
      for (int rt = 0; rt < 4; ++rt) {
        const int jr = jb + rt * 16 + quad * 4;
        #pragma unroll
        for (int reg = 0; reg < 4; ++reg)
          if (jr + reg < len) part += acc[rt][lo][reg];
      }
      part += __shfl_xor(part, 16);            // quad ^ 1
      part += __shfl_xor(part, 32);            // quad ^ 2
      if (quad == 0) atomicAdd(mvg + bidx * DKD + d, part);
    }
  }
}

// ---------------------------------------------------------------------------
// attn: flash attention, 64 q-rows/block, pipelined 64-key blocks (dbuf DMA).
// BATCH-FASTEST flat grid: b = blockIdx&15, q-tile reversed (heavy first) ->
// heavy blocks of ALL batches dispatch first, interleaved (CU load balance).
// l accumulated as a 9th PV tile vs a ones-B fragment. Fully-padded query
// blocks broadcast mvg[b]/len. s_setprio(1) around MFMA clusters (T5).
// ---------------------------------------------------------------------------
__global__ __launch_bounds__(256, 2) void attn(
    const unsigned short* __restrict__ Qw, const unsigned short* __restrict__ Kz,
    const unsigned short* __restrict__ Vz, const float* __restrict__ mvg,
    const int* __restrict__ lens, float* __restrict__ out)
{
  __shared__ unsigned short Ks[2][64 * 128];   // [j][16 chunks x 8], swz c^(j&15)
  __shared__ unsigned short Vs[2][128 * 64];   // [d][8 chunks x 8],  swz c^(d&7)
  __shared__ unsigned short Ps[4][16 * 72];    // per-wave P [q][j+pad8]
  const int tid = threadIdx.x;
  const int wave = tid >> 6, lane = tid & 63;
  const int quad = lane >> 4, mm = lane & 15;
  const int b = (int)blockIdx.x & 15;          // batch fastest -> balance
  const int qb = (31 - ((int)blockIdx.x >> 4)) * 64;  // heavy tiles first
  const int len = lens[b];

  if (qb >= len) {
    // ---- mean path: every row = mvg[b]/len (precomputed by proj V path) ----
    const int dd = (tid & 31) * 4;
    const int r0 = tid >> 5;                 // 0..7
    const f32x4 m4 = *(const f32x4*)(mvg + b * DKD + dd);
    const float inv = 1.0f / (float)len;
    const f32x4 val = f32x4{ m4[0]*inv, m4[1]*inv, m4[2]*inv, m4[3]*inv };
    #pragma unroll
    for (int it = 0; it < 8; ++it) {
      const int row = qb + it * 8 + r0;
      *(f32x4*)(out + ((size_t)b * SL + row) * DKD + dd) = val;
    }
    return;
  }

  const int kend = min(qb + 64, len);
  const int nblk = (kend + 63) >> 6;
  const int irow0 = qb + wave * 16 + quad * 4;

  bf16x8 aQ[4];
  {
    const unsigned short* qbase =
        Qw + (size_t)(b * SL + qb + wave * 16 + mm) * DKD + quad * 8;
    #pragma unroll
    for (int cc = 0; cc < 4; ++cc) aQ[cc] = *(const bf16x8*)(qbase + cc * 32);
  }
  bf16x8 onesb;
  #pragma unroll
  for (int i = 0; i < 8; ++i) onesb[i] = (__bf16)1.0f;

  float mr[4];
  #pragma unroll
  for (int r = 0; r < 4; ++r) mr[r] = -__builtin_inff();
  f32x4 acc[8];
  #pragma unroll
  for (int i = 0; i < 8; ++i) acc[i] = f32x4{0.f,0.f,0.f,0.f};
  f32x4 accl = f32x4{0.f,0.f,0.f,0.f};       // l = P @ ones, rescaled with acc

  // prologue DMA: block 0 -> buf 0
  #pragma unroll
  for (int it = 0; it < 4; ++it) {
    int s = it * 256 + tid;
    dma16(Kz + (size_t)(b * SL) * DKD + (size_t)s * 8,
          (char*)Ks[0] + (it * 256 + wave * 64) * 16);
  }
  #pragma unroll
  for (int it = 0; it < 4; ++it) {
    int s = it * 256 + tid;
    int d = s >> 3, p = s & 7;
    dma16(Vz + (size_t)b * DKD * SL + (size_t)d * SL + p * 8,
          (char*)Vs[0] + (it * 256 + wave * 64) * 16);
  }

  #pragma unroll 1
  for (int blk = 0; blk < nblk; ++blk) {
    const int kb = blk * 64;
    __syncthreads();                       // drains DMA(blk)
    if (blk + 1 < nblk) {                  // issue next block's DMA
      const int kb1 = kb + 64;
      const int nb = (blk + 1) & 1;
      #pragma unroll
      for (int it = 0; it < 4; ++it) {
        int s = it * 256 + tid;
        dma16(Kz + (size_t)(b * SL + kb1) * DKD + (size_t)s * 8,
              (char*)Ks[nb] + (it * 256 + wave * 64) * 16);
      }
      #pragma unroll
      for (int it = 0; it < 4; ++it) {
        int s = it * 256 + tid;
        int d = s >> 3, p = s & 7;
        dma16(Vz + (size_t)b * DKD * SL + (size_t)d * SL + kb1 + p * 8,
              (char*)Vs[nb] + (it * 256 + wave * 64) * 16);
      }
    }
    const unsigned short* kbuf = Ks[blk & 1];
    const unsigned short* vbuf = Vs[blk & 1];

    // S = Q K^T : 4 key-tiles
    f32x4 s4[4];
    __builtin_amdgcn_s_setprio(1);
    #pragma unroll
    for (int nt = 0; nt < 4; ++nt) {
      f32x4 c = f32x4{0.f,0.f,0.f,0.f};
      const int j = nt * 16 + mm;
      #pragma unroll
      for (int cc = 0; cc < 4; ++cc) {
        const int pp = (cc * 4 + quad) ^ mm;
        bf16x8 kf = *(const bf16x8*)(kbuf + j * 128 + pp * 8);
        c = mfma16(aQ[cc], kf, c);
      }
      s4[nt] = c;
    }
    __builtin_amdgcn_s_setprio(0);

    float alpha[4];
    #pragma unroll
    for (int reg = 0; reg < 4; ++reg) {
      const int jl = min(irow0 + reg + 1, len);
      float v0 = (kb + mm      < jl) ? s4[0][reg] : -__builtin_inff();
      float v1 = (kb + 16 + mm < jl) ? s4[1][reg] : -__builtin_inff();
      float v2 = (kb + 32 + mm < jl) ? s4[2][reg] : -__builtin_inff();
      float v3 = (kb + 48 + mm < jl) ? s4[3][reg] : -__builtin_inff();
      float mx = fmaxf(fmaxf(v0, v1), fmaxf(v2, v3));
      #pragma unroll
      for (int xm = 1; xm < 16; xm <<= 1) mx = fmaxf(mx, __shfl_xor(mx, xm));
      const float mn = fmaxf(mr[reg], mx);
      alpha[reg] = __builtin_amdgcn_exp2f(mr[reg] - mn);
      const float p0 = __builtin_amdgcn_exp2f(v0 - mn);
      const float p1 = __builtin_amdgcn_exp2f(v1 - mn);
      const float p2 = __builtin_amdgcn_exp2f(v2 - mn);
      const float p3 = __builtin_amdgcn_exp2f(v3 - mn);
      mr[reg] = mn;
      const int prow = quad * 4 + reg;
      Ps[wave][prow * 72 + mm]      = f2bf(p0);
      Ps[wave][prow * 72 + 16 + mm] = f2bf(p1);
      Ps[wave][prow * 72 + 32 + mm] = f2bf(p2);
      Ps[wave][prow * 72 + 48 + mm] = f2bf(p3);
    }
    #pragma unroll
    for (int nt = 0; nt < 8; ++nt) {
      f32x4 a = acc[nt];
      a[0] *= alpha[0]; a[1] *= alpha[1]; a[2] *= alpha[2]; a[3] *= alpha[3];
      acc[nt] = a;
    }
    accl[0] *= alpha[0]; accl[1] *= alpha[1];
    accl[2] *= alpha[2]; accl[3] *= alpha[3];
    __asm__ volatile("s_waitcnt lgkmcnt(0)" ::: "memory");  // P writes -> reads
    bf16x8 aP[2];
    #pragma unroll
    for (int ks = 0; ks < 2; ++ks)
      aP[ks] = *(const bf16x8*)(&Ps[wave][mm * 72 + ks * 32 + quad * 8]);
    __builtin_amdgcn_s_setprio(1);
    #pragma unroll
    for (int ks = 0; ks < 2; ++ks) {
      #pragma unroll
      for (int nt = 0; nt < 8; ++nt) {
        const int pp = (ks * 4 + quad) ^ (mm & 7);
        bf16x8 vf = *(const bf16x8*)(vbuf + (nt * 16 + mm) * 64 + pp * 8);
        acc[nt] = mfma16(aP[ks], vf, acc[nt]);
      }
      accl = mfma16(aP[ks], onesb, accl);    // row-sum tile (all cols equal)
    }
    __builtin_amdgcn_s_setprio(0);
  }

  #pragma unroll
  for (int reg = 0; reg < 4; ++reg) {
    const float rl = 1.0f / accl[reg];
    const size_t base = ((size_t)b * SL + irow0 + reg) * DKD + mm;
    #pragma unroll
    for (int nt = 0; nt < 8; ++nt)
      out[base + nt * 16] = acc[nt][reg] * rl;
  }
}

// ---------------------------------------------------------------------------
extern "C" void kernel_launch(void* const* d_in, const int* in_sizes, int n_in,
                              void* d_out, int out_size, void* d_ws, size_t ws_size,
                              hipStream_t stream) {
  const float* x    = (const float*)d_in[0];
  const float* ctx  = (const float*)d_in[1];
  const int*   lens = (const int*)d_in[2];
  const float* Wq   = (const float*)d_in[3];
  const float* Wk   = (const float*)d_in[4];
  const float* Wv   = (const float*)d_in[5];
  float* out = (float*)d_out;

  const size_t QKV = (size_t)NB * SL * DKD * sizeof(unsigned short); // 8 MiB each
  const size_t WTSZ = (size_t)3 * 16 * 128 * 8 * 8 * sizeof(unsigned short); // 768 KiB
  const size_t MVSZ = (size_t)NB * DKD * sizeof(float);              // 8 KiB
  if (ws_size < 3 * QKV + WTSZ + MVSZ) return;
  unsigned short* Qws = (unsigned short*)d_ws;
  unsigned short* Kzs = (unsigned short*)((char*)d_ws + QKV);
  unsigned short* Vzs = (unsigned short*)((char*)d_ws + 2 * QKV);
  unsigned short* Wt  = (unsigned short*)((char*)d_ws + 3 * QKV);
  float*          mvg = (float*)((char*)d_ws + 3 * QKV + WTSZ);

  prep_w<<<dim3(48), 256, 0, stream>>>(Wq, Wk, Wv, Wt, mvg);
  proj  <<<dim3(2 * NB * SL / 64), 256, 0, stream>>>(ctx, x, Wt, lens,
                                                     Qws, Kzs, Vzs, mvg);
  attn  <<<dim3(NB * SL / 64), 256, 0, stream>>>(Qws, Kzs, Vzs, mvg, lens, out);
}

// Round 8
// 348.426 us; speedup vs baseline: 1.0368x; 1.0368x over previous
//
#include <hip/hip_runtime.h>

#define DEV __device__ __forceinline__

typedef __attribute__((ext_vector_type(4))) float f32x4;
typedef __attribute__((ext_vector_type(4))) unsigned short u16x4;
typedef __attribute__((ext_vector_type(8))) __bf16 bf16x8;

constexpr int NB = 16, SL = 2048, EM = 1024, DKD = 128;

DEV unsigned short f2bf(float f) {           // fp32 -> bf16 RNE
  unsigned int u = __float_as_uint(f);
  u += 0x7FFFu + ((u >> 16) & 1u);
  return (unsigned short)(u >> 16);
}

DEV f32x4 mfma16(bf16x8 a, bf16x8 b, f32x4 c) {
  return __builtin_amdgcn_mfma_f32_16x16x32_bf16(a, b, c, 0, 0, 0);
}

// async global->LDS DMA, 16B per lane; lds dst = wave-uniform base + lane*16
DEV void dma16(const void* g, void* l) {
  __builtin_amdgcn_global_load_lds(
      (const __attribute__((address_space(1))) unsigned int*)g,
      (__attribute__((address_space(3))) unsigned int*)l, 16, 0, 0);
}

DEV bf16x8 cvt8(f32x4 a, f32x4 b) {
  bf16x8 r;
  r[0] = (__bf16)a[0]; r[1] = (__bf16)a[1]; r[2] = (__bf16)a[2]; r[3] = (__bf16)a[3];
  r[4] = (__bf16)b[0]; r[5] = (__bf16)b[1]; r[6] = (__bf16)b[2]; r[7] = (__bf16)b[3];
  return r;
}

#define SBAR() __builtin_amdgcn_sched_barrier(0)

// ---------------------------------------------------------------------------
// prep_w: Wq/Wk/Wv fp32 [1024][128] -> bf16, tiled+swizzled. Block 0 also
// zeroes the mean-V accumulator mvg[NB][128].
// Chunk t = ((m*16 + kc)*128 + n)*8 + p holds W_m[k = kc*64 + (p^(n&7))*8 + e][n].
// ---------------------------------------------------------------------------
__global__ __launch_bounds__(256) void prep_w(
    const float* __restrict__ Wq, const float* __restrict__ Wk,
    const float* __restrict__ Wv, unsigned short* __restrict__ Wt,
    float* __restrict__ mvg)
{
  __shared__ unsigned short T[64 * 128];     // [kk][n] bf16
  const int tid = threadIdx.x;
  if (blockIdx.x == 0) {
    #pragma unroll
    for (int i = 0; i < NB * DKD / 256; ++i) mvg[i * 256 + tid] = 0.f;
  }
  const int m = blockIdx.x >> 4, kc = blockIdx.x & 15;   // 48 blocks
  const float* W = (m == 0) ? Wq : ((m == 1) ? Wk : Wv);
  #pragma unroll
  for (int it = 0; it < 8; ++it) {
    int idx = it * 256 + tid;                // 2048 f32x4 chunks
    int kk = idx >> 5, n4 = (idx & 31) * 4;
    f32x4 w4 = *(const f32x4*)(W + (size_t)(kc * 64 + kk) * DKD + n4);
    *(u16x4*)&T[kk * 128 + n4] =
        u16x4{ f2bf(w4[0]), f2bf(w4[1]), f2bf(w4[2]), f2bf(w4[3]) };
  }
  __syncthreads();
  #pragma unroll
  for (int it = 0; it < 4; ++it) {
    int idx = it * 256 + tid;                // 1024 out chunks, p fastest
    int p = idx & 7, n = idx >> 3;
    int c = p ^ (n & 7);
    unsigned short v[8];
    #pragma unroll
    for (int e = 0; e < 8; ++e) v[e] = T[(c * 8 + e) * 128 + n];
    size_t t = ((size_t)(m * 16 + kc) * 128 + n) * 8 + p;
    *(u16x4*)(Wt + t * 8)     = u16x4{v[0], v[1], v[2], v[3]};
    *(u16x4*)(Wt + t * 8 + 4) = u16x4{v[4], v[5], v[6], v[7]};
  }
}

// ---------------------------------------------------------------------------
// proj_qk: Q,K = ctx @ {Wq,Wk}. M-tile 64 (grid 512). Dead blocks return.
// 4-buffer A pipeline, TWO K-steps per barrier window (halves sync cost/kc):
//   step s (kc0=2s, kc1=2s+1), steady-state VMEM queue at step top:
//     [B(kc0) x8, B(kc1) x8, A(kc0+2) x4, A(kc0+3) x4]   (24)
//   a: ds_read af0 <- Als[kc0&3]; MFMA(kc0) x bA  [compiler vmcnt drains B(kc0)]
//   c: reload bA <- B(kc0+2)
//   d: ds_read af1 <- Als[kc1&3]; MFMA(kc1) x bB  [drains B(kc1)]
//   f: reload bB <- B(kc0+3)
//   g: lgkmcnt(0); barrier    (buffers kc0&3, kc1&3 free)
//   i: DMA A(kc0+4)->Als[kc0&3], A(kc0+5)->Als[kc1&3]
//   j: vmcnt(24)              (drains exactly A(kc0+2),A(kc0+3); B+new A ride)
//   k: barrier (publish)
// Prologue shaped to the same queue; tails clamped so counts stay uniform.
// SBAR pins keep issue-order groups intact (hand counts depend on it).
// ---------------------------------------------------------------------------
__global__ __launch_bounds__(256, 2) void proj_qk(
    const float* __restrict__ ctx, const unsigned short* __restrict__ Wt,
    const int* __restrict__ lens, unsigned short* __restrict__ Qo,
    unsigned short* __restrict__ Kz)
{
  __shared__ float Als[4][64 * 64];            // 64 KiB A 4-buf
  const int tid = threadIdx.x;
  const int wave = tid >> 6, lane = tid & 63;
  const int quad = lane >> 4, mm = lane & 15;
  const int rb = blockIdx.x * 64;
  const int len = lens[blockIdx.x >> 5];
  if ((rb & (SL - 1)) >= len) return;          // dead block: outputs never read

  f32x4 acc[4][4];
  #pragma unroll
  for (int i = 0; i < 4; ++i)
    #pragma unroll
    for (int j = 0; j < 4; ++j) acc[i][j] = f32x4{0.f, 0.f, 0.f, 0.f};

  // A-DMA source: instr i covers rows wave*16+i*4+(lane>>4); slot s=lane&15
  // sources chunk c=(s&8)|((s&7)^(row&7))  (involution, undone on read).
  const float* asrc[4];
  #pragma unroll
  for (int i = 0; i < 4; ++i) {
    const int rl_ = wave * 16 + i * 4 + (lane >> 4);
    const int cc  = (lane & 8) | ((lane & 7) ^ (rl_ & 7));
    asrc[i] = ctx + (size_t)(rb + rl_) * EM + cc * 4;
  }
  int soff[2][2];
  #pragma unroll
  for (int ks = 0; ks < 2; ++ks) {
    soff[ks][0] = (ks * 8 + ((quad * 2)     ^ (mm & 7))) * 4;
    soff[ks][1] = (ks * 8 + ((quad * 2 + 1) ^ (mm & 7))) * 4;
  }
  const unsigned short* bbase[4][2];
  #pragma unroll
  for (int lo = 0; lo < 4; ++lo)
    #pragma unroll
    for (int ks = 0; ks < 2; ++ks) {
      const int nrow = (wave * 4 + lo) * 16 + mm;
      const int pp = (ks * 4 + quad) ^ (mm & 7);
      const int cs = nrow * 8 + pp;
      bbase[lo][ks] = Wt + ((size_t)(cs >> 10) * 16384 + (cs & 1023)) * 8;
    }

  // ---- prologue: DMA A0,A1 | load B0,B1 | DMA A2,A3 | vmcnt(24) drains A0,A1
  #pragma unroll
  for (int i = 0; i < 4; ++i) dma16(asrc[i],       (char*)Als[0] + wave * 4096 + i * 1024);
  #pragma unroll
  for (int i = 0; i < 4; ++i) dma16(asrc[i] + 64,  (char*)Als[1] + wave * 4096 + i * 1024);
  SBAR();
  bf16x8 bA[4][2], bB[4][2];
  #pragma unroll
  for (int lo = 0; lo < 4; ++lo)
    #pragma unroll
    for (int ks = 0; ks < 2; ++ks) {
      bA[lo][ks] = *(const bf16x8*)(bbase[lo][ks]);
      bB[lo][ks] = *(const bf16x8*)(bbase[lo][ks] + 8192);
    }
  SBAR();
  #pragma unroll
  for (int i = 0; i < 4; ++i) dma16(asrc[i] + 128, (char*)Als[2] + wave * 4096 + i * 1024);
  #pragma unroll
  for (int i = 0; i < 4; ++i) dma16(asrc[i] + 192, (char*)Als[3] + wave * 4096 + i * 1024);
  SBAR();
  __asm__ volatile("s_waitcnt vmcnt(24)" ::: "memory");
  __builtin_amdgcn_s_barrier();
  SBAR();

  #pragma unroll 1
  for (int s = 0; s < 8; ++s) {
    const int kc0 = 2 * s, kc1 = 2 * s + 1;
    // a: kc0 fragments + MFMA
    bf16x8 af0[4][2];
    #pragma unroll
    for (int rt = 0; rt < 4; ++rt) {
      const float* rbase = Als[kc0 & 3] + (rt * 16 + mm) * 64;
      #pragma unroll
      for (int ks = 0; ks < 2; ++ks)
        af0[rt][ks] = cvt8(*(const f32x4*)(rbase + soff[ks][0]),
                           *(const f32x4*)(rbase + soff[ks][1]));
    }
    #pragma unroll
    for (int lo = 0; lo < 4; ++lo)
      #pragma unroll
      for (int ks = 0; ks < 2; ++ks)
        #pragma unroll
        for (int rt = 0; rt < 4; ++rt)
          acc[rt][lo] = mfma16(af0[rt][ks], bA[lo][ks], acc[rt][lo]);
    // c: reload bA <- B(kc0+2)
    {
      const int kn = (kc0 + 2 < 16) ? (kc0 + 2) : 15;
      #pragma unroll
      for (int lo = 0; lo < 4; ++lo)
        #pragma unroll
        for (int ks = 0; ks < 2; ++ks)
          bA[lo][ks] = *(const bf16x8*)(bbase[lo][ks] + (size_t)kn * 8192);
    }
    // d: kc1 fragments + MFMA
    bf16x8 af1[4][2];
    #pragma unroll
    for (int rt = 0; rt < 4; ++rt) {
      const float* rbase = Als[kc1 & 3] + (rt * 16 + mm) * 64;
      #pragma unroll
      for (int ks = 0; ks < 2; ++ks)
        af1[rt][ks] = cvt8(*(const f32x4*)(rbase + soff[ks][0]),
                           *(const f32x4*)(rbase + soff[ks][1]));
    }
    #pragma unroll
    for (int lo = 0; lo < 4; ++lo)
      #pragma unroll
      for (int ks = 0; ks < 2; ++ks)
        #pragma unroll
        for (int rt = 0; rt < 4; ++rt)
          acc[rt][lo] = mfma16(af1[rt][ks], bB[lo][ks], acc[rt][lo]);
    // f: reload bB <- B(kc0+3)
    {
      const int kn = (kc0 + 3 < 16) ? (kc0 + 3) : 15;
      #pragma unroll
      for (int lo = 0; lo < 4; ++lo)
        #pragma unroll
        for (int ks = 0; ks < 2; ++ks)
          bB[lo][ks] = *(const bf16x8*)(bbase[lo][ks] + (size_t)kn * 8192);
    }
    // g/h: buffers kc0&3,kc1&3 free
    __asm__ volatile("s_waitcnt lgkmcnt(0)" ::: "memory");
    SBAR();
    __builtin_amdgcn_s_barrier();
    // i: DMA next pair into the freed buffers (clamped tail)
    {
      const int k4 = (kc0 + 4 < 16) ? (kc0 + 4) : 15;
      const int k5 = (kc0 + 5 < 16) ? (kc0 + 5) : 15;
      #pragma unroll
      for (int i = 0; i < 4; ++i)
        dma16(asrc[i] + k4 * 64, (char*)Als[kc0 & 3] + wave * 4096 + i * 1024);
      #pragma unroll
      for (int i = 0; i < 4; ++i)
        dma16(asrc[i] + k5 * 64, (char*)Als[kc1 & 3] + wave * 4096 + i * 1024);
    }
    // j/k: drain exactly the 2-step-old A-DMAs; publish
    __asm__ volatile("s_waitcnt vmcnt(24)" ::: "memory");
    __builtin_amdgcn_s_barrier();
    SBAR();
  }
  __asm__ volatile("s_waitcnt vmcnt(0)" ::: "memory");   // drain clamped tails

  const float SCALE = 1.4426950408889634f * 0.08838834764831845f; // log2e/sqrt(128)
  #pragma unroll
  for (int rt = 0; rt < 4; ++rt)
    #pragma unroll
    for (int lo = 0; lo < 4; ++lo) {
      const int ctg = wave * 4 + lo;
      #pragma unroll
      for (int reg = 0; reg < 4; ++reg) {
        const int row = rb + rt * 16 + quad * 4 + reg;
        const int j = row & (SL - 1);
        const float val = acc[rt][lo][reg];
        if (ctg < 8) {
          const int d = ctg * 16 + mm;
          Qo[(size_t)row * DKD + d] = f2bf(val * ((j < len) ? SCALE : 0.f));
        } else {
          const int d = (ctg - 8) * 16 + mm;
          Kz[(size_t)row * DKD + (((d >> 3) ^ (j & 15)) * 8) + (d & 7)] = f2bf(val);
        }
      }
    }
}

// ---------------------------------------------------------------------------
// proj_v: V = x @ Wv, same 2-step pipeline (B x4/kc -> j wait = vmcnt(16)).
// Epilogue: V store + per-batch column-sum into mvg (one atomic per d).
// ---------------------------------------------------------------------------
__global__ __launch_bounds__(256, 2) void proj_v(
    const float* __restrict__ x, const unsigned short* __restrict__ Wt,
    const int* __restrict__ lens, unsigned short* __restrict__ Vz,
    float* __restrict__ mvg)
{
  __shared__ float Als[4][64 * 64];            // 64 KiB A 4-buf
  const int tid = threadIdx.x;
  const int wave = tid >> 6, lane = tid & 63;
  const int quad = lane >> 4, mm = lane & 15;
  const int rb = blockIdx.x * 64;
  const int bidx = blockIdx.x >> 5;
  const int len = lens[bidx];
  if ((rb & (SL - 1)) >= len) return;          // dead block: outputs never read

  f32x4 acc[4][2];
  #pragma unroll
  for (int i = 0; i < 4; ++i) { acc[i][0] = f32x4{0.f,0.f,0.f,0.f}; acc[i][1] = f32x4{0.f,0.f,0.f,0.f}; }

  const float* asrc[4];
  #pragma unroll
  for (int i = 0; i < 4; ++i) {
    const int rl_ = wave * 16 + i * 4 + (lane >> 4);
    const int cc  = (lane & 8) | ((lane & 7) ^ (rl_ & 7));
    asrc[i] = x + (size_t)(rb + rl_) * EM + cc * 4;
  }
  int soff[2][2];
  #pragma unroll
  for (int ks = 0; ks < 2; ++ks) {
    soff[ks][0] = (ks * 8 + ((quad * 2)     ^ (mm & 7))) * 4;
    soff[ks][1] = (ks * 8 + ((quad * 2 + 1) ^ (mm & 7))) * 4;
  }
  const unsigned short* bbase[2][2];
  #pragma unroll
  for (int lo = 0; lo < 2; ++lo)
    #pragma unroll
    for (int ks = 0; ks < 2; ++ks) {
      const int nrow = (wave * 2 + lo) * 16 + mm;
      const int pp = (ks * 4 + quad) ^ (mm & 7);
      const int cs = nrow * 8 + pp;            // cs < 1024
      bbase[lo][ks] = Wt + ((size_t)2 * 16384 + cs) * 8;
    }

  // ---- prologue (queue shaped like steady state) ----
  #pragma unroll
  for (int i = 0; i < 4; ++i) dma16(asrc[i],       (char*)Als[0] + wave * 4096 + i * 1024);
  #pragma unroll
  for (int i = 0; i < 4; ++i) dma16(asrc[i] + 64,  (char*)Als[1] + wave * 4096 + i * 1024);
  SBAR();
  bf16x8 bA[2][2], bB[2][2];
  #pragma unroll
  for (int lo = 0; lo < 2; ++lo)
    #pragma unroll
    for (int ks = 0; ks < 2; ++ks) {
      bA[lo][ks] = *(const bf16x8*)(bbase[lo][ks]);
      bB[lo][ks] = *(const bf16x8*)(bbase[lo][ks] + 8192);
    }
  SBAR();
  #pragma unroll
  for (int i = 0; i < 4; ++i) dma16(asrc[i] + 128, (char*)Als[2] + wave * 4096 + i * 1024);
  #pragma unroll
  for (int i = 0; i < 4; ++i) dma16(asrc[i] + 192, (char*)Als[3] + wave * 4096 + i * 1024);
  SBAR();
  __asm__ volatile("s_waitcnt vmcnt(16)" ::: "memory");
  __builtin_amdgcn_s_barrier();
  SBAR();

  #pragma unroll 1
  for (int s = 0; s < 8; ++s) {
    const int kc0 = 2 * s, kc1 = 2 * s + 1;
    bf16x8 af0[4][2];
    #pragma unroll
    for (int rt = 0; rt < 4; ++rt) {
      const float* rbase = Als[kc0 & 3] + (rt * 16 + mm) * 64;
      #pragma unroll
      for (int ks = 0; ks < 2; ++ks)
        af0[rt][ks] = cvt8(*(const f32x4*)(rbase + soff[ks][0]),
                           *(const f32x4*)(rbase + soff[ks][1]));
    }
    #pragma unroll
    for (int lo = 0; lo < 2; ++lo)
      #pragma unroll
      for (int ks = 0; ks < 2; ++ks)
        #pragma unroll
        for (int rt = 0; rt < 4; ++rt)
          acc[rt][lo] = mfma16(af0[rt][ks], bA[lo][ks], acc[rt][lo]);
    {
      const int kn = (kc0 + 2 < 16) ? (kc0 + 2) : 15;
      #pragma unroll
      for (int lo = 0; lo < 2; ++lo)
        #pragma unroll
        for (int ks = 0; ks < 2; ++ks)
          bA[lo][ks] = *(const bf16x8*)(bbase[lo][ks] + (size_t)kn * 8192);
    }
    bf16x8 af1[4][2];
    #pragma unroll
    for (int rt = 0; rt < 4; ++rt) {
      const float* rbase = Als[kc1 & 3] + (rt * 16 + mm) * 64;
      #pragma unroll
      for (int ks = 0; ks < 2; ++ks)
        af1[rt][ks] = cvt8(*(const f32x4*)(rbase + soff[ks][0]),
                           *(const f32x4*)(rbase + soff[ks][1]));
    }
    #pragma unroll
    for (int lo = 0; lo < 2; ++lo)
      #pragma unroll
      for (int ks = 0; ks < 2; ++ks)
        #pragma unroll
        for (int rt = 0; rt < 4; ++rt)
          acc[rt][lo] = mfma16(af1[rt][ks], bB[lo][ks], acc[rt][lo]);
    {
      const int kn = (kc0 + 3 < 16) ? (kc0 + 3) : 15;
      #pragma unroll
      for (int lo = 0; lo < 2; ++lo)
        #pragma unroll
        for (int ks = 0; ks < 2; ++ks)
          bB[lo][ks] = *(const bf16x8*)(bbase[lo][ks] + (size_t)kn * 8192);
    }
    __asm__ volatile("s_waitcnt lgkmcnt(0)" ::: "memory");
    SBAR();
    __builtin_amdgcn_s_barrier();
    {
      const int k4 = (kc0 + 4 < 16) ? (kc0 + 4) : 15;
      const int k5 = (kc0 + 5 < 16) ? (kc0 + 5) : 15;
      #pragma unroll
      for (int i = 0; i < 4; ++i)
        dma16(asrc[i] + k4 * 64, (char*)Als[kc0 & 3] + wave * 4096 + i * 1024);
      #pragma unroll
      for (int i = 0; i < 4; ++i)
        dma16(asrc[i] + k5 * 64, (char*)Als[kc1 & 3] + wave * 4096 + i * 1024);
    }
    __asm__ volatile("s_waitcnt vmcnt(16)" ::: "memory");
    __builtin_amdgcn_s_barrier();
    SBAR();
  }
  __asm__ volatile("s_waitcnt vmcnt(0)" ::: "memory");

  #pragma unroll
  for (int rt = 0; rt < 4; ++rt)
    #pragma unroll
    for (int lo = 0; lo < 2; ++lo) {
      const int d = (wave * 2 + lo) * 16 + mm;
      const int row0 = rb + rt * 16 + quad * 4;
      const int b = row0 >> 11, j0 = row0 & (SL - 1);
      u16x4 pk = u16x4{ f2bf(acc[rt][lo][0]), f2bf(acc[rt][lo][1]),
                        f2bf(acc[rt][lo][2]), f2bf(acc[rt][lo][3]) };
      size_t off = (size_t)b * DKD * SL + (size_t)d * SL + (j0 & ~63)
                 + ((((j0 >> 3) & 7) ^ (d & 7)) * 8) + (j0 & 7);
      *(u16x4*)(Vz + off) = pk;
    }

  // mean-V accumulation: sum valid rows (j < len), f32, one atomic/(d)
  const int jb = rb & (SL - 1);
  #pragma unroll
  for (int lo = 0; lo < 2; ++lo) {
    const int d = (wave * 2 + lo) * 16 + mm;
    float part = 0.f;
    #pragma unroll
    for (int rt = 0; rt < 4; ++rt) {
      const int jr = jb + rt * 16 + quad * 4;
      #pragma unroll
      for (int reg = 0; reg < 4; ++reg)
        if (jr + reg < len) part += acc[rt][lo][reg];
    }
    part += __shfl_xor(part, 16);            // quad ^ 1
    part += __shfl_xor(part, 32);            // quad ^ 2
    if (quad == 0) atomicAdd(mvg + bidx * DKD + d, part);
  }
}

// ---------------------------------------------------------------------------
// attn: flash attention, 64 q-rows/block, pipelined 64-key blocks (dbuf DMA).
// l accumulated as a 9th PV tile vs a ones-B fragment. Fully-padded query
// blocks broadcast mvg[b]/len. s_setprio(1) around MFMA clusters (T5).
// ---------------------------------------------------------------------------
__global__ __launch_bounds__(256, 2) void attn(
    const unsigned short* __restrict__ Qw, const unsigned short* __restrict__ Kz,
    const unsigned short* __restrict__ Vz, const float* __restrict__ mvg,
    const int* __restrict__ lens, float* __restrict__ out)
{
  __shared__ unsigned short Ks[2][64 * 128];   // [j][16 chunks x 8], swz c^(j&15)
  __shared__ unsigned short Vs[2][128 * 64];   // [d][8 chunks x 8],  swz c^(d&7)
  __shared__ unsigned short Ps[4][16 * 72];    // per-wave P [q][j+pad8]
  const int tid = threadIdx.x;
  const int wave = tid >> 6, lane = tid & 63;
  const int quad = lane >> 4, mm = lane & 15;
  const int b = blockIdx.y;
  const int qb = ((int)gridDim.x - 1 - (int)blockIdx.x) * 64;  // heavy blocks first
  const int len = lens[b];

  if (qb >= len) {
    // ---- mean path: every row = mvg[b]/len (precomputed by proj_v) ----
    const int dd = (tid & 31) * 4;
    const int r0 = tid >> 5;                 // 0..7
    const f32x4 m4 = *(const f32x4*)(mvg + b * DKD + dd);
    const float inv = 1.0f / (float)len;
    const f32x4 val = f32x4{ m4[0]*inv, m4[1]*inv, m4[2]*inv, m4[3]*inv };
    #pragma unroll
    for (int it = 0; it < 8; ++it) {
      const int row = qb + it * 8 + r0;
      *(f32x4*)(out + ((size_t)b * SL + row) * DKD + dd) = val;
    }
    return;
  }

  const int kend = min(qb + 64, len);
  const int nblk = (kend + 63) >> 6;
  const int irow0 = qb + wave * 16 + quad * 4;

  bf16x8 aQ[4];
  {
    const unsigned short* qbase =
        Qw + (size_t)(b * SL + qb + wave * 16 + mm) * DKD + quad * 8;
    #pragma unroll
    for (int cc = 0; cc < 4; ++cc) aQ[cc] = *(const bf16x8*)(qbase + cc * 32);
  }
  bf16x8 onesb;
  #pragma unroll
  for (int i = 0; i < 8; ++i) onesb[i] = (__bf16)1.0f;

  float mr[4];
  #pragma unroll
  for (int r = 0; r < 4; ++r) mr[r] = -__builtin_inff();
  f32x4 acc[8];
  #pragma unroll
  for (int i = 0; i < 8; ++i) acc[i] = f32x4{0.f,0.f,0.f,0.f};
  f32x4 accl = f32x4{0.f,0.f,0.f,0.f};       // l = P @ ones, rescaled with acc

  // prologue DMA: block 0 -> buf 0
  #pragma unroll
  for (int it = 0; it < 4; ++it) {
    int s = it * 256 + tid;
    dma16(Kz + (size_t)(b * SL) * DKD + (size_t)s * 8,
          (char*)Ks[0] + (it * 256 + wave * 64) * 16);
  }
  #pragma unroll
  for (int it = 0; it < 4; ++it) {
    int s = it * 256 + tid;
    int d = s >> 3, p = s & 7;
    dma16(Vz + (size_t)b * DKD * SL + (size_t)d * SL + p * 8,
          (char*)Vs[0] + (it * 256 + wave * 64) * 16);
  }

  #pragma unroll 1
  for (int blk = 0; blk < nblk; ++blk) {
    const int kb = blk * 64;
    __syncthreads();                       // drains DMA(blk)
    if (blk + 1 < nblk) {                  // issue next block's DMA
      const int kb1 = kb + 64;
      const int nb = (blk + 1) & 1;
      #pragma unroll
      for (int it = 0; it < 4; ++it) {
        int s = it * 256 + tid;
        dma16(Kz + (size_t)(b * SL + kb1) * DKD + (size_t)s * 8,
              (char*)Ks[nb] + (it * 256 + wave * 64) * 16);
      }
      #pragma unroll
      for (int it = 0; it < 4; ++it) {
        int s = it * 256 + tid;
        int d = s >> 3, p = s & 7;
        dma16(Vz + (size_t)b * DKD * SL + (size_t)d * SL + kb1 + p * 8,
              (char*)Vs[nb] + (it * 256 + wave * 64) * 16);
      }
    }
    const unsigned short* kbuf = Ks[blk & 1];
    const unsigned short* vbuf = Vs[blk & 1];

    // S = Q K^T : 4 key-tiles
    f32x4 s4[4];
    __builtin_amdgcn_s_setprio(1);
    #pragma unroll
    for (int nt = 0; nt < 4; ++nt) {
      f32x4 c = f32x4{0.f,0.f,0.f,0.f};
      const int j = nt * 16 + mm;
      #pragma unroll
      for (int cc = 0; cc < 4; ++cc) {
        const int pp = (cc * 4 + quad) ^ mm;
        bf16x8 kf = *(const bf16x8*)(kbuf + j * 128 + pp * 8);
        c = mfma16(aQ[cc], kf, c);
      }
      s4[nt] = c;
    }
    __builtin_amdgcn_s_setprio(0);

    float alpha[4];
    #pragma unroll
    for (int reg = 0; reg < 4; ++reg) {
      const int jl = min(irow0 + reg + 1, len);
      float v0 = (kb + mm      < jl) ? s4[0][reg] : -__builtin_inff();
      float v1 = (kb + 16 + mm < jl) ? s4[1][reg] : -__builtin_inff();
      float v2 = (kb + 32 + mm < jl) ? s4[2][reg] : -__builtin_inff();
      float v3 = (kb + 48 + mm < jl) ? s4[3][reg] : -__builtin_inff();
      float mx = fmaxf(fmaxf(v0, v1), fmaxf(v2, v3));
      #pragma unroll
      for (int xm = 1; xm < 16; xm <<= 1) mx = fmaxf(mx, __shfl_xor(mx, xm));
      const float mn = fmaxf(mr[reg], mx);
      alpha[reg] = __builtin_amdgcn_exp2f(mr[reg] - mn);
      const float p0 = __builtin_amdgcn_exp2f(v0 - mn);
      const float p1 = __builtin_amdgcn_exp2f(v1 - mn);
      const float p2 = __builtin_amdgcn_exp2f(v2 - mn);
      const float p3 = __builtin_amdgcn_exp2f(v3 - mn);
      mr[reg] = mn;
      const int prow = quad * 4 + reg;
      Ps[wave][prow * 72 + mm]      = f2bf(p0);
      Ps[wave][prow * 72 + 16 + mm] = f2bf(p1);
      Ps[wave][prow * 72 + 32 + mm] = f2bf(p2);
      Ps[wave][prow * 72 + 48 + mm] = f2bf(p3);
    }
    #pragma unroll
    for (int nt = 0; nt < 8; ++nt) {
      f32x4 a = acc[nt];
      a[0] *= alpha[0]; a[1] *= alpha[1]; a[2] *= alpha[2]; a[3] *= alpha[3];
      acc[nt] = a;
    }
    accl[0] *= alpha[0]; accl[1] *= alpha[1];
    accl[2] *= alpha[2]; accl[3] *= alpha[3];
    __asm__ volatile("s_waitcnt lgkmcnt(0)" ::: "memory");  // P writes -> reads
    bf16x8 aP[2];
    #pragma unroll
    for (int ks = 0; ks < 2; ++ks)
      aP[ks] = *(const bf16x8*)(&Ps[wave][mm * 72 + ks * 32 + quad * 8]);
    __builtin_amdgcn_s_setprio(1);
    #pragma unroll
    for (int ks = 0; ks < 2; ++ks) {
      #pragma unroll
      for (int nt = 0; nt < 8; ++nt) {
        const int pp = (ks * 4 + quad) ^ (mm & 7);
        bf16x8 vf = *(const bf16x8*)(vbuf + (nt * 16 + mm) * 64 + pp * 8);
        acc[nt] = mfma16(aP[ks], vf, acc[nt]);
      }
      accl = mfma16(aP[ks], onesb, accl);    // row-sum tile (all cols equal)
    }
    __builtin_amdgcn_s_setprio(0);
  }

  #pragma unroll
  for (int reg = 0; reg < 4; ++reg) {
    const float rl = 1.0f / accl[reg];
    const size_t base = ((size_t)b * SL + irow0 + reg) * DKD + mm;
    #pragma unroll
    for (int nt = 0; nt < 8; ++nt)
      out[base + nt * 16] = acc[nt][reg] * rl;
  }
}

// ---------------------------------------------------------------------------
extern "C" void kernel_launch(void* const* d_in, const int* in_sizes, int n_in,
                              void* d_out, int out_size, void* d_ws, size_t ws_size,
                              hipStream_t stream) {
  const float* x    = (const float*)d_in[0];
  const float* ctx  = (const float*)d_in[1];
  const int*   lens = (const int*)d_in[2];
  const float* Wq   = (const float*)d_in[3];
  const float* Wk   = (const float*)d_in[4];
  const float* Wv   = (const float*)d_in[5];
  float* out = (float*)d_out;

  const size_t QKV = (size_t)NB * SL * DKD * sizeof(unsigned short); // 8 MiB each
  const size_t WTSZ = (size_t)3 * 16 * 128 * 8 * 8 * sizeof(unsigned short); // 768 KiB
  const size_t MVSZ = (size_t)NB * DKD * sizeof(float);              // 8 KiB
  if (ws_size < 3 * QKV + WTSZ + MVSZ) return;
  unsigned short* Qws = (unsigned short*)d_ws;
  unsigned short* Kzs = (unsigned short*)((char*)d_ws + QKV);
  unsigned short* Vzs = (unsigned short*)((char*)d_ws + 2 * QKV);
  unsigned short* Wt  = (unsigned short*)((char*)d_ws + 3 * QKV);
  float*          mvg = (float*)((char*)d_ws + 3 * QKV + WTSZ);

  prep_w <<<dim3(48), 256, 0, stream>>>(Wq, Wk, Wv, Wt, mvg);
  proj_qk<<<dim3(NB * SL / 64), 256, 0, stream>>>(ctx, Wt, lens, Qws, Kzs);
  proj_v <<<dim3(NB * SL / 64), 256, 0, stream>>>(x, Wt, lens, Vzs, mvg);
  attn   <<<dim3(SL / 64, NB), 256, 0, stream>>>(Qws, Kzs, Vzs, mvg, lens, out);
}

// Round 9
// 333.442 us; speedup vs baseline: 1.0834x; 1.0449x over previous
//
#include <hip/hip_runtime.h>

#define DEV __device__ __forceinline__

typedef __attribute__((ext_vector_type(4))) float f32x4;
typedef __attribute__((ext_vector_type(4))) unsigned short u16x4;
typedef __attribute__((ext_vector_type(8))) __bf16 bf16x8;

constexpr int NB = 16, SL = 2048, EM = 1024, DKD = 128;

DEV unsigned short f2bf(float f) {           // fp32 -> bf16 RNE
  unsigned int u = __float_as_uint(f);
  u += 0x7FFFu + ((u >> 16) & 1u);
  return (unsigned short)(u >> 16);
}

DEV f32x4 mfma16(bf16x8 a, bf16x8 b, f32x4 c) {
  return __builtin_amdgcn_mfma_f32_16x16x32_bf16(a, b, c, 0, 0, 0);
}

// async global->LDS DMA, 16B per lane; lds dst = wave-uniform base + lane*16
DEV void dma16(const void* g, void* l) {
  __builtin_amdgcn_global_load_lds(
      (const __attribute__((address_space(1))) unsigned int*)g,
      (__attribute__((address_space(3))) unsigned int*)l, 16, 0, 0);
}

DEV bf16x8 cvt8(f32x4 a, f32x4 b) {
  bf16x8 r;
  r[0] = (__bf16)a[0]; r[1] = (__bf16)a[1]; r[2] = (__bf16)a[2]; r[3] = (__bf16)a[3];
  r[4] = (__bf16)b[0]; r[5] = (__bf16)b[1]; r[6] = (__bf16)b[2]; r[7] = (__bf16)b[3];
  return r;
}

#define SBAR() __builtin_amdgcn_sched_barrier(0)

// ---------------------------------------------------------------------------
// prep_w: Wq/Wk/Wv fp32 [1024][128] -> bf16, tiled+swizzled. Block 0 also
// zeroes the mean-V accumulator mvg[NB][128].
// Chunk t = ((m*16 + kc)*128 + n)*8 + p holds W_m[k = kc*64 + (p^(n&7))*8 + e][n].
// ---------------------------------------------------------------------------
__global__ __launch_bounds__(256) void prep_w(
    const float* __restrict__ Wq, const float* __restrict__ Wk,
    const float* __restrict__ Wv, unsigned short* __restrict__ Wt,
    float* __restrict__ mvg)
{
  __shared__ unsigned short T[64 * 128];     // [kk][n] bf16
  const int tid = threadIdx.x;
  if (blockIdx.x == 0) {
    #pragma unroll
    for (int i = 0; i < NB * DKD / 256; ++i) mvg[i * 256 + tid] = 0.f;
  }
  const int m = blockIdx.x >> 4, kc = blockIdx.x & 15;   // 48 blocks
  const float* W = (m == 0) ? Wq : ((m == 1) ? Wk : Wv);
  #pragma unroll
  for (int it = 0; it < 8; ++it) {
    int idx = it * 256 + tid;                // 2048 f32x4 chunks
    int kk = idx >> 5, n4 = (idx & 31) * 4;
    f32x4 w4 = *(const f32x4*)(W + (size_t)(kc * 64 + kk) * DKD + n4);
    *(u16x4*)&T[kk * 128 + n4] =
        u16x4{ f2bf(w4[0]), f2bf(w4[1]), f2bf(w4[2]), f2bf(w4[3]) };
  }
  __syncthreads();
  #pragma unroll
  for (int it = 0; it < 4; ++it) {
    int idx = it * 256 + tid;                // 1024 out chunks, p fastest
    int p = idx & 7, n = idx >> 3;
    int c = p ^ (n & 7);
    unsigned short v[8];
    #pragma unroll
    for (int e = 0; e < 8; ++e) v[e] = T[(c * 8 + e) * 128 + n];
    size_t t = ((size_t)(m * 16 + kc) * 128 + n) * 8 + p;
    *(u16x4*)(Wt + t * 8)     = u16x4{v[0], v[1], v[2], v[3]};
    *(u16x4*)(Wt + t * 8 + 4) = u16x4{v[4], v[5], v[6], v[7]};
  }
}

// ---------------------------------------------------------------------------
// proj_qk: Q,K = ctx @ {Wq,Wk}. M-tile 64 (grid 512). Dead blocks return.
// 4-buffer A pipeline, TWO K-steps per barrier window. B dbuf'd in registers
// from the L2-resident pre-swizzled Wt. Counted vmcnt (see r8 notes).
// ---------------------------------------------------------------------------
__global__ __launch_bounds__(256, 2) void proj_qk(
    const float* __restrict__ ctx, const unsigned short* __restrict__ Wt,
    const int* __restrict__ lens, unsigned short* __restrict__ Qo,
    unsigned short* __restrict__ Kz)
{
  __shared__ float Als[4][64 * 64];            // 64 KiB A 4-buf
  const int tid = threadIdx.x;
  const int wave = tid >> 6, lane = tid & 63;
  const int quad = lane >> 4, mm = lane & 15;
  const int rb = blockIdx.x * 64;
  const int len = lens[blockIdx.x >> 5];
  if ((rb & (SL - 1)) >= len) return;          // dead block: outputs never read

  f32x4 acc[4][4];
  #pragma unroll
  for (int i = 0; i < 4; ++i)
    #pragma unroll
    for (int j = 0; j < 4; ++j) acc[i][j] = f32x4{0.f, 0.f, 0.f, 0.f};

  const float* asrc[4];
  #pragma unroll
  for (int i = 0; i < 4; ++i) {
    const int rl_ = wave * 16 + i * 4 + (lane >> 4);
    const int cc  = (lane & 8) | ((lane & 7) ^ (rl_ & 7));
    asrc[i] = ctx + (size_t)(rb + rl_) * EM + cc * 4;
  }
  int soff[2][2];
  #pragma unroll
  for (int ks = 0; ks < 2; ++ks) {
    soff[ks][0] = (ks * 8 + ((quad * 2)     ^ (mm & 7))) * 4;
    soff[ks][1] = (ks * 8 + ((quad * 2 + 1) ^ (mm & 7))) * 4;
  }
  const unsigned short* bbase[4][2];
  #pragma unroll
  for (int lo = 0; lo < 4; ++lo)
    #pragma unroll
    for (int ks = 0; ks < 2; ++ks) {
      const int nrow = (wave * 4 + lo) * 16 + mm;
      const int pp = (ks * 4 + quad) ^ (mm & 7);
      const int cs = nrow * 8 + pp;
      bbase[lo][ks] = Wt + ((size_t)(cs >> 10) * 16384 + (cs & 1023)) * 8;
    }

  #pragma unroll
  for (int i = 0; i < 4; ++i) dma16(asrc[i],       (char*)Als[0] + wave * 4096 + i * 1024);
  #pragma unroll
  for (int i = 0; i < 4; ++i) dma16(asrc[i] + 64,  (char*)Als[1] + wave * 4096 + i * 1024);
  SBAR();
  bf16x8 bA[4][2], bB[4][2];
  #pragma unroll
  for (int lo = 0; lo < 4; ++lo)
    #pragma unroll
    for (int ks = 0; ks < 2; ++ks) {
      bA[lo][ks] = *(const bf16x8*)(bbase[lo][ks]);
      bB[lo][ks] = *(const bf16x8*)(bbase[lo][ks] + 8192);
    }
  SBAR();
  #pragma unroll
  for (int i = 0; i < 4; ++i) dma16(asrc[i] + 128, (char*)Als[2] + wave * 4096 + i * 1024);
  #pragma unroll
  for (int i = 0; i < 4; ++i) dma16(asrc[i] + 192, (char*)Als[3] + wave * 4096 + i * 1024);
  SBAR();
  __asm__ volatile("s_waitcnt vmcnt(24)" ::: "memory");
  __builtin_amdgcn_s_barrier();
  SBAR();

  #pragma unroll 1
  for (int s = 0; s < 8; ++s) {
    const int kc0 = 2 * s, kc1 = 2 * s + 1;
    bf16x8 af0[4][2];
    #pragma unroll
    for (int rt = 0; rt < 4; ++rt) {
      const float* rbase = Als[kc0 & 3] + (rt * 16 + mm) * 64;
      #pragma unroll
      for (int ks = 0; ks < 2; ++ks)
        af0[rt][ks] = cvt8(*(const f32x4*)(rbase + soff[ks][0]),
                           *(const f32x4*)(rbase + soff[ks][1]));
    }
    #pragma unroll
    for (int lo = 0; lo < 4; ++lo)
      #pragma unroll
      for (int ks = 0; ks < 2; ++ks)
        #pragma unroll
        for (int rt = 0; rt < 4; ++rt)
          acc[rt][lo] = mfma16(af0[rt][ks], bA[lo][ks], acc[rt][lo]);
    {
      const int kn = (kc0 + 2 < 16) ? (kc0 + 2) : 15;
      #pragma unroll
      for (int lo = 0; lo < 4; ++lo)
        #pragma unroll
        for (int ks = 0; ks < 2; ++ks)
          bA[lo][ks] = *(const bf16x8*)(bbase[lo][ks] + (size_t)kn * 8192);
    }
    bf16x8 af1[4][2];
    #pragma unroll
    for (int rt = 0; rt < 4; ++rt) {
      const float* rbase = Als[kc1 & 3] + (rt * 16 + mm) * 64;
      #pragma unroll
      for (int ks = 0; ks < 2; ++ks)
        af1[rt][ks] = cvt8(*(const f32x4*)(rbase + soff[ks][0]),
                           *(const f32x4*)(rbase + soff[ks][1]));
    }
    #pragma unroll
    for (int lo = 0; lo < 4; ++lo)
      #pragma unroll
      for (int ks = 0; ks < 2; ++ks)
        #pragma unroll
        for (int rt = 0; rt < 4; ++rt)
          acc[rt][lo] = mfma16(af1[rt][ks], bB[lo][ks], acc[rt][lo]);
    {
      const int kn = (kc0 + 3 < 16) ? (kc0 + 3) : 15;
      #pragma unroll
      for (int lo = 0; lo < 4; ++lo)
        #pragma unroll
        for (int ks = 0; ks < 2; ++ks)
          bB[lo][ks] = *(const bf16x8*)(bbase[lo][ks] + (size_t)kn * 8192);
    }
    __asm__ volatile("s_waitcnt lgkmcnt(0)" ::: "memory");
    SBAR();
    __builtin_amdgcn_s_barrier();
    {
      const int k4 = (kc0 + 4 < 16) ? (kc0 + 4) : 15;
      const int k5 = (kc0 + 5 < 16) ? (kc0 + 5) : 15;
      #pragma unroll
      for (int i = 0; i < 4; ++i)
        dma16(asrc[i] + k4 * 64, (char*)Als[kc0 & 3] + wave * 4096 + i * 1024);
      #pragma unroll
      for (int i = 0; i < 4; ++i)
        dma16(asrc[i] + k5 * 64, (char*)Als[kc1 & 3] + wave * 4096 + i * 1024);
    }
    __asm__ volatile("s_waitcnt vmcnt(24)" ::: "memory");
    __builtin_amdgcn_s_barrier();
    SBAR();
  }
  __asm__ volatile("s_waitcnt vmcnt(0)" ::: "memory");   // drain clamped tails

  const float SCALE = 1.4426950408889634f * 0.08838834764831845f; // log2e/sqrt(128)
  #pragma unroll
  for (int rt = 0; rt < 4; ++rt)
    #pragma unroll
    for (int lo = 0; lo < 4; ++lo) {
      const int ctg = wave * 4 + lo;
      #pragma unroll
      for (int reg = 0; reg < 4; ++reg) {
        const int row = rb + rt * 16 + quad * 4 + reg;
        const int j = row & (SL - 1);
        const float val = acc[rt][lo][reg];
        if (ctg < 8) {
          const int d = ctg * 16 + mm;
          Qo[(size_t)row * DKD + d] = f2bf(val * ((j < len) ? SCALE : 0.f));
        } else {
          const int d = (ctg - 8) * 16 + mm;
          Kz[(size_t)row * DKD + (((d >> 3) ^ (j & 15)) * 8) + (d & 7)] = f2bf(val);
        }
      }
    }
}

// ---------------------------------------------------------------------------
// proj_v: V = x @ Wv, same 2-step pipeline (B x4/kc -> vmcnt(16)).
// Epilogue: V store + per-batch column-sum into mvg (one atomic per d).
// ---------------------------------------------------------------------------
__global__ __launch_bounds__(256, 2) void proj_v(
    const float* __restrict__ x, const unsigned short* __restrict__ Wt,
    const int* __restrict__ lens, unsigned short* __restrict__ Vz,
    float* __restrict__ mvg)
{
  __shared__ float Als[4][64 * 64];            // 64 KiB A 4-buf
  const int tid = threadIdx.x;
  const int wave = tid >> 6, lane = tid & 63;
  const int quad = lane >> 4, mm = lane & 15;
  const int rb = blockIdx.x * 64;
  const int bidx = blockIdx.x >> 5;
  const int len = lens[bidx];
  if ((rb & (SL - 1)) >= len) return;          // dead block: outputs never read

  f32x4 acc[4][2];
  #pragma unroll
  for (int i = 0; i < 4; ++i) { acc[i][0] = f32x4{0.f,0.f,0.f,0.f}; acc[i][1] = f32x4{0.f,0.f,0.f,0.f}; }

  const float* asrc[4];
  #pragma unroll
  for (int i = 0; i < 4; ++i) {
    const int rl_ = wave * 16 + i * 4 + (lane >> 4);
    const int cc  = (lane & 8) | ((lane & 7) ^ (rl_ & 7));
    asrc[i] = x + (size_t)(rb + rl_) * EM + cc * 4;
  }
  int soff[2][2];
  #pragma unroll
  for (int ks = 0; ks < 2; ++ks) {
    soff[ks][0] = (ks * 8 + ((quad * 2)     ^ (mm & 7))) * 4;
    soff[ks][1] = (ks * 8 + ((quad * 2 + 1) ^ (mm & 7))) * 4;
  }
  const unsigned short* bbase[2][2];
  #pragma unroll
  for (int lo = 0; lo < 2; ++lo)
    #pragma unroll
    for (int ks = 0; ks < 2; ++ks) {
      const int nrow = (wave * 2 + lo) * 16 + mm;
      const int pp = (ks * 4 + quad) ^ (mm & 7);
      const int cs = nrow * 8 + pp;            // cs < 1024
      bbase[lo][ks] = Wt + ((size_t)2 * 16384 + cs) * 8;
    }

  #pragma unroll
  for (int i = 0; i < 4; ++i) dma16(asrc[i],       (char*)Als[0] + wave * 4096 + i * 1024);
  #pragma unroll
  for (int i = 0; i < 4; ++i) dma16(asrc[i] + 64,  (char*)Als[1] + wave * 4096 + i * 1024);
  SBAR();
  bf16x8 bA[2][2], bB[2][2];
  #pragma unroll
  for (int lo = 0; lo < 2; ++lo)
    #pragma unroll
    for (int ks = 0; ks < 2; ++ks) {
      bA[lo][ks] = *(const bf16x8*)(bbase[lo][ks]);
      bB[lo][ks] = *(const bf16x8*)(bbase[lo][ks] + 8192);
    }
  SBAR();
  #pragma unroll
  for (int i = 0; i < 4; ++i) dma16(asrc[i] + 128, (char*)Als[2] + wave * 4096 + i * 1024);
  #pragma unroll
  for (int i = 0; i < 4; ++i) dma16(asrc[i] + 192, (char*)Als[3] + wave * 4096 + i * 1024);
  SBAR();
  __asm__ volatile("s_waitcnt vmcnt(16)" ::: "memory");
  __builtin_amdgcn_s_barrier();
  SBAR();

  #pragma unroll 1
  for (int s = 0; s < 8; ++s) {
    const int kc0 = 2 * s, kc1 = 2 * s + 1;
    bf16x8 af0[4][2];
    #pragma unroll
    for (int rt = 0; rt < 4; ++rt) {
      const float* rbase = Als[kc0 & 3] + (rt * 16 + mm) * 64;
      #pragma unroll
      for (int ks = 0; ks < 2; ++ks)
        af0[rt][ks] = cvt8(*(const f32x4*)(rbase + soff[ks][0]),
                           *(const f32x4*)(rbase + soff[ks][1]));
    }
    #pragma unroll
    for (int lo = 0; lo < 2; ++lo)
      #pragma unroll
      for (int ks = 0; ks < 2; ++ks)
        #pragma unroll
        for (int rt = 0; rt < 4; ++rt)
          acc[rt][lo] = mfma16(af0[rt][ks], bA[lo][ks], acc[rt][lo]);
    {
      const int kn = (kc0 + 2 < 16) ? (kc0 + 2) : 15;
      #pragma unroll
      for (int lo = 0; lo < 2; ++lo)
        #pragma unroll
        for (int ks = 0; ks < 2; ++ks)
          bA[lo][ks] = *(const bf16x8*)(bbase[lo][ks] + (size_t)kn * 8192);
    }
    bf16x8 af1[4][2];
    #pragma unroll
    for (int rt = 0; rt < 4; ++rt) {
      const float* rbase = Als[kc1 & 3] + (rt * 16 + mm) * 64;
      #pragma unroll
      for (int ks = 0; ks < 2; ++ks)
        af1[rt][ks] = cvt8(*(const f32x4*)(rbase + soff[ks][0]),
                           *(const f32x4*)(rbase + soff[ks][1]));
    }
    #pragma unroll
    for (int lo = 0; lo < 2; ++lo)
      #pragma unroll
      for (int ks = 0; ks < 2; ++ks)
        #pragma unroll
        for (int rt = 0; rt < 4; ++rt)
          acc[rt][lo] = mfma16(af1[rt][ks], bB[lo][ks], acc[rt][lo]);
    {
      const int kn = (kc0 + 3 < 16) ? (kc0 + 3) : 15;
      #pragma unroll
      for (int lo = 0; lo < 2; ++lo)
        #pragma unroll
        for (int ks = 0; ks < 2; ++ks)
          bB[lo][ks] = *(const bf16x8*)(bbase[lo][ks] + (size_t)kn * 8192);
    }
    __asm__ volatile("s_waitcnt lgkmcnt(0)" ::: "memory");
    SBAR();
    __builtin_amdgcn_s_barrier();
    {
      const int k4 = (kc0 + 4 < 16) ? (kc0 + 4) : 15;
      const int k5 = (kc0 + 5 < 16) ? (kc0 + 5) : 15;
      #pragma unroll
      for (int i = 0; i < 4; ++i)
        dma16(asrc[i] + k4 * 64, (char*)Als[kc0 & 3] + wave * 4096 + i * 1024);
      #pragma unroll
      for (int i = 0; i < 4; ++i)
        dma16(asrc[i] + k5 * 64, (char*)Als[kc1 & 3] + wave * 4096 + i * 1024);
    }
    __asm__ volatile("s_waitcnt vmcnt(16)" ::: "memory");
    __builtin_amdgcn_s_barrier();
    SBAR();
  }
  __asm__ volatile("s_waitcnt vmcnt(0)" ::: "memory");

  #pragma unroll
  for (int rt = 0; rt < 4; ++rt)
    #pragma unroll
    for (int lo = 0; lo < 2; ++lo) {
      const int d = (wave * 2 + lo) * 16 + mm;
      const int row0 = rb + rt * 16 + quad * 4;
      const int b = row0 >> 11, j0 = row0 & (SL - 1);
      u16x4 pk = u16x4{ f2bf(acc[rt][lo][0]), f2bf(acc[rt][lo][1]),
                        f2bf(acc[rt][lo][2]), f2bf(acc[rt][lo][3]) };
      size_t off = (size_t)b * DKD * SL + (size_t)d * SL + (j0 & ~63)
                 + ((((j0 >> 3) & 7) ^ (d & 7)) * 8) + (j0 & 7);
      *(u16x4*)(Vz + off) = pk;
    }

  // mean-V accumulation: sum valid rows (j < len), f32, one atomic/(d)
  const int jb = rb & (SL - 1);
  #pragma unroll
  for (int lo = 0; lo < 2; ++lo) {
    const int d = (wave * 2 + lo) * 16 + mm;
    float part = 0.f;
    #pragma unroll
    for (int rt = 0; rt < 4; ++rt) {
      const int jr = jb + rt * 16 + quad * 4;
      #pragma unroll
      for (int reg = 0; reg < 4; ++reg)
        if (jr + reg < len) part += acc[rt][lo][reg];
    }
    part += __shfl_xor(part, 16);            // quad ^ 1
    part += __shfl_xor(part, 32);            // quad ^ 2
    if (quad == 0) atomicAdd(mvg + bidx * DKD + d, part);
  }
}

// ---------------------------------------------------------------------------
// attn: flash attention, split-k within block. 512 threads / 8 waves:
// wg=wave&3 owns 16 q-rows; wh=wave>>2 owns one 64-wide k-half of each
// 128-wide k-block. Each half keeps independent online-softmax state
// (mr, accl, acc); merged ONCE at the end (exact f32 merge) reusing the
// dead K-LDS as scratch. Halves the heavy block's serial iteration count
// (32 -> 16). All-masked tiles guarded via mn clamp to -1e30 (no NaN).
// ---------------------------------------------------------------------------
__global__ __launch_bounds__(512, 2) void attn(
    const unsigned short* __restrict__ Qw, const unsigned short* __restrict__ Kz,
    const unsigned short* __restrict__ Vz, const float* __restrict__ mvg,
    const int* __restrict__ lens, float* __restrict__ out)
{
  __shared__ unsigned short Ks[2][128 * 128];    // [j][16 chunks x 8], swz c^(j&15); 64 KiB
  __shared__ unsigned short Vs[2][2][128 * 64];  // [buf][half][d][8 chunks x 8], swz c^(d&7); 64 KiB
  __shared__ unsigned short Ps[8][16 * 72];      // per-wave P [q][j+pad8]; 18 KiB
  const int tid = threadIdx.x;
  const int wave = tid >> 6, lane = tid & 63;
  const int quad = lane >> 4, mm = lane & 15;
  const int wg = wave & 3;                       // q-row group
  const int wh = wave >> 2;                      // k-half
  const int b = blockIdx.y;
  const int qb = ((int)gridDim.x - 1 - (int)blockIdx.x) * 64;  // heavy blocks first
  const int len = lens[b];

  if (qb >= len) {
    // ---- mean path: every row = mvg[b]/len (precomputed by proj_v) ----
    const int dd = (tid & 31) * 4;
    const int r0 = tid >> 5;                     // 0..15
    const f32x4 m4 = *(const f32x4*)(mvg + b * DKD + dd);
    const float inv = 1.0f / (float)len;
    const f32x4 val = f32x4{ m4[0]*inv, m4[1]*inv, m4[2]*inv, m4[3]*inv };
    #pragma unroll
    for (int it = 0; it < 4; ++it) {
      const int row = qb + it * 16 + r0;
      *(f32x4*)(out + ((size_t)b * SL + row) * DKD + dd) = val;
    }
    return;
  }

  const int kend = min(qb + 64, len);
  const int nblk = (kend + 127) >> 7;            // 128-wide k-blocks
  const int irow0 = qb + wg * 16 + quad * 4;

  bf16x8 aQ[4];
  {
    const unsigned short* qbase =
        Qw + (size_t)(b * SL + qb + wg * 16 + mm) * DKD + quad * 8;
    #pragma unroll
    for (int cc = 0; cc < 4; ++cc) aQ[cc] = *(const bf16x8*)(qbase + cc * 32);
  }
  bf16x8 onesb;
  #pragma unroll
  for (int i = 0; i < 8; ++i) onesb[i] = (__bf16)1.0f;

  float mr[4];
  #pragma unroll
  for (int r = 0; r < 4; ++r) mr[r] = -__builtin_inff();
  f32x4 acc[8];
  #pragma unroll
  for (int i = 0; i < 8; ++i) acc[i] = f32x4{0.f,0.f,0.f,0.f};
  f32x4 accl = f32x4{0.f,0.f,0.f,0.f};           // l = P @ ones (this half)

  // prologue DMA: k-block 0 -> buf 0 (K: 2048 chunks; V: 2 halves x 1024)
  #pragma unroll
  for (int it = 0; it < 4; ++it) {
    int s = it * 512 + tid;
    dma16(Kz + (size_t)(b * SL) * DKD + (size_t)s * 8,
          (char*)Ks[0] + (it * 512 + wave * 64) * 16);
  }
  #pragma unroll
  for (int h = 0; h < 2; ++h)
    #pragma unroll
    for (int it = 0; it < 2; ++it) {
      int s = it * 512 + tid;
      int d = s >> 3, p = s & 7;
      dma16(Vz + (size_t)b * DKD * SL + (size_t)d * SL + h * 64 + p * 8,
            (char*)Vs[0][h] + (it * 512 + wave * 64) * 16);
    }

  #pragma unroll 1
  for (int blk = 0; blk < nblk; ++blk) {
    const int kb = blk * 128;
    __syncthreads();                             // drains DMA(blk)
    if (blk + 1 < nblk) {                        // issue next block's DMA
      const int kb1 = kb + 128;
      const int nb = (blk + 1) & 1;
      #pragma unroll
      for (int it = 0; it < 4; ++it) {
        int s = it * 512 + tid;
        dma16(Kz + (size_t)(b * SL + kb1) * DKD + (size_t)s * 8,
              (char*)Ks[nb] + (it * 512 + wave * 64) * 16);
      }
      #pragma unroll
      for (int h = 0; h < 2; ++h)
        #pragma unroll
        for (int it = 0; it < 2; ++it) {
          int s = it * 512 + tid;
          int d = s >> 3, p = s & 7;
          dma16(Vz + (size_t)b * DKD * SL + (size_t)d * SL + (kb1 + h * 64) + p * 8,
                (char*)Vs[nb][h] + (it * 512 + wave * 64) * 16);
        }
    }
    const unsigned short* kbuf = Ks[blk & 1];
    const unsigned short* vbuf = Vs[blk & 1][wh];
    const int kbh = kb + wh * 64;                // this wave's k-window start

    // S = Q K^T over this half's 64 keys
    f32x4 s4[4];
    __builtin_amdgcn_s_setprio(1);
    #pragma unroll
    for (int nt = 0; nt < 4; ++nt) {
      f32x4 c = f32x4{0.f,0.f,0.f,0.f};
      const int j = wh * 64 + nt * 16 + mm;      // row in kbuf
      #pragma unroll
      for (int cc = 0; cc < 4; ++cc) {
        const int pp = (cc * 4 + quad) ^ mm;
        bf16x8 kf = *(const bf16x8*)(kbuf + j * 128 + pp * 8);
        c = mfma16(aQ[cc], kf, c);
      }
      s4[nt] = c;
    }
    __builtin_amdgcn_s_setprio(0);

    float alpha[4];
    #pragma unroll
    for (int reg = 0; reg < 4; ++reg) {
      const int jl = min(irow0 + reg + 1, len);
      float v0 = (kbh + mm      < jl) ? s4[0][reg] : -__builtin_inff();
      float v1 = (kbh + 16 + mm < jl) ? s4[1][reg] : -__builtin_inff();
      float v2 = (kbh + 32 + mm < jl) ? s4[2][reg] : -__builtin_inff();
      float v3 = (kbh + 48 + mm < jl) ? s4[3][reg] : -__builtin_inff();
      float mx = fmaxf(fmaxf(v0, v1), fmaxf(v2, v3));
      #pragma unroll
      for (int xm = 1; xm < 16; xm <<= 1) mx = fmaxf(mx, __shfl_xor(mx, xm));
      // clamp: all-masked tiles (upper half before causal frontier) would give
      // mn=-inf and NaN in exp2(mr-mn); -1e30 makes alpha and all p exact 0.
      const float mn = fmaxf(fmaxf(mr[reg], mx), -1e30f);
      alpha[reg] = __builtin_amdgcn_exp2f(mr[reg] - mn);
      const float p0 = __builtin_amdgcn_exp2f(v0 - mn);
      const float p1 = __builtin_amdgcn_exp2f(v1 - mn);
      const float p2 = __builtin_amdgcn_exp2f(v2 - mn);
      const float p3 = __builtin_amdgcn_exp2f(v3 - mn);
      mr[reg] = mn;
      const int prow = quad * 4 + reg;
      Ps[wave][prow * 72 + mm]      = f2bf(p0);
      Ps[wave][prow * 72 + 16 + mm] = f2bf(p1);
      Ps[wave][prow * 72 + 32 + mm] = f2bf(p2);
      Ps[wave][prow * 72 + 48 + mm] = f2bf(p3);
    }
    #pragma unroll
    for (int nt = 0; nt < 8; ++nt) {
      f32x4 a = acc[nt];
      a[0] *= alpha[0]; a[1] *= alpha[1]; a[2] *= alpha[2]; a[3] *= alpha[3];
      acc[nt] = a;
    }
    accl[0] *= alpha[0]; accl[1] *= alpha[1];
    accl[2] *= alpha[2]; accl[3] *= alpha[3];
    __asm__ volatile("s_waitcnt lgkmcnt(0)" ::: "memory");  // P writes -> reads
    bf16x8 aP[2];
    #pragma unroll
    for (int ks = 0; ks < 2; ++ks)
      aP[ks] = *(const bf16x8*)(&Ps[wave][mm * 72 + ks * 32 + quad * 8]);
    __builtin_amdgcn_s_setprio(1);
    #pragma unroll
    for (int ks = 0; ks < 2; ++ks) {
      #pragma unroll
      for (int nt = 0; nt < 8; ++nt) {
        const int pp = (ks * 4 + quad) ^ (mm & 7);
        bf16x8 vf = *(const bf16x8*)(vbuf + (nt * 16 + mm) * 64 + pp * 8);
        acc[nt] = mfma16(aP[ks], vf, acc[nt]);
      }
      accl = mfma16(aP[ks], onesb, accl);        // row-sum tile
    }
    __builtin_amdgcn_s_setprio(0);
  }

  // ---- merge halves (wh=1 -> LDS scratch in dead Ks; wh=0 merges+writes) ----
  __syncthreads();                               // all compute done; Ks dead
  float* mrg = (float*)&Ks[0][0];                // 41*256*4 = 41 KiB <= 64 KiB
  if (wh == 1) {
    float* p = mrg + (wg * 64 + lane) * 41;
    #pragma unroll
    for (int r = 0; r < 4; ++r) p[r] = mr[r];
    #pragma unroll
    for (int r = 0; r < 4; ++r) p[4 + r] = accl[r];
    #pragma unroll
    for (int nt = 0; nt < 8; ++nt)
      #pragma unroll
      for (int r = 0; r < 4; ++r) p[8 + nt * 4 + r] = acc[nt][r];
  }
  __syncthreads();
  if (wh == 0) {
    const float* p = mrg + (wg * 64 + lane) * 41;
    #pragma unroll
    for (int reg = 0; reg < 4; ++reg) {
      const float m1 = p[reg], l1 = p[4 + reg];
      const float m = fmaxf(mr[reg], m1);
      const float f0 = __builtin_amdgcn_exp2f(mr[reg] - m);
      const float f1 = __builtin_amdgcn_exp2f(m1 - m);
      const float rl = 1.0f / (accl[reg] * f0 + l1 * f1);
      const size_t base = ((size_t)b * SL + irow0 + reg) * DKD + mm;
      #pragma unroll
      for (int nt = 0; nt < 8; ++nt)
        out[base + nt * 16] = (acc[nt][reg] * f0 + p[8 + nt * 4 + reg] * f1) * rl;
    }
  }
}

// ---------------------------------------------------------------------------
extern "C" void kernel_launch(void* const* d_in, const int* in_sizes, int n_in,
                              void* d_out, int out_size, void* d_ws, size_t ws_size,
                              hipStream_t stream) {
  const float* x    = (const float*)d_in[0];
  const float* ctx  = (const float*)d_in[1];
  const int*   lens = (const int*)d_in[2];
  const float* Wq   = (const float*)d_in[3];
  const float* Wk   = (const float*)d_in[4];
  const float* Wv   = (const float*)d_in[5];
  float* out = (float*)d_out;

  const size_t QKV = (size_t)NB * SL * DKD * sizeof(unsigned short); // 8 MiB each
  const size_t WTSZ = (size_t)3 * 16 * 128 * 8 * 8 * sizeof(unsigned short); // 768 KiB
  const size_t MVSZ = (size_t)NB * DKD * sizeof(float);              // 8 KiB
  if (ws_size < 3 * QKV + WTSZ + MVSZ) return;
  unsigned short* Qws = (unsigned short*)d_ws;
  unsigned short* Kzs = (unsigned short*)((char*)d_ws + QKV);
  unsigned short* Vzs = (unsigned short*)((char*)d_ws + 2 * QKV);
  unsigned short* Wt  = (unsigned short*)((char*)d_ws + 3 * QKV);
  float*          mvg = (float*)((char*)d_ws + 3 * QKV + WTSZ);

  prep_w <<<dim3(48), 256, 0, stream>>>(Wq, Wk, Wv, Wt, mvg);
  proj_qk<<<dim3(NB * SL / 64), 256, 0, stream>>>(ctx, Wt, lens, Qws, Kzs);
  proj_v <<<dim3(NB * SL / 64), 256, 0, stream>>>(x, Wt, lens, Vzs, mvg);
  attn   <<<dim3(SL / 64, NB), 512, 0, stream>>>(Qws, Kzs, Vzs, mvg, lens, out);
}